// Round 15
// baseline (648.958 us; speedup 1.0000x reference)
//
#include <hip/hip_runtime.h>

typedef __attribute__((ext_vector_type(4))) float f32x4;
typedef __attribute__((ext_vector_type(8))) short bf16x8;
typedef __attribute__((ext_vector_type(8))) unsigned short ushort8;

#define NB 16
#define NC 128
#define NT 8
#define NN 1024
#define INV_T (1.0f/0.07f)

// k-permutation sigma: within each 64-col block of every k-indexed fp8 buffer
// (G, P, M), natural col c = n*16+l is stored at byte position l*4+n. Both GEMM
// operands use sigma => contraction unchanged.

__device__ __forceinline__ unsigned short f2bf(float x){
  union { float f; unsigned int u; } v; v.f = x;
  unsigned int r = v.u + 0x7fffu + ((v.u >> 16) & 1u);
  return (unsigned short)(r >> 16);
}

__device__ __forceinline__ unsigned char f2fp8_sw(float x){
  if(!(x >= 9.765625e-4f)) return 0;
  if(x >= 448.f) return 0x7E;
  union { float f; unsigned int u; } v; v.f = x;
  int e = (int)((v.u >> 23) & 255) - 127;
  if(e >= -6){
    unsigned int m = v.u & 0x7FFFFFu;
    unsigned int r = m + 0x7FFFFu + ((m >> 20) & 1u);
    if(r & 0x800000u){ e++; r = 0; }
    unsigned int b = ((unsigned)(e + 7) << 3) | ((r >> 20) & 7u);
    if(b >= 0x7Fu) b = 0x7Eu;
    return (unsigned char)b;
  } else {
    float t = x * 512.f;
    int q = (int)(t + 0.5f);
    return (unsigned char)q;
  }
}

__device__ __forceinline__ unsigned int pk2fp8(float a, float b){
#if __has_builtin(__builtin_amdgcn_cvt_pk_fp8_f32)
  return (unsigned int)__builtin_amdgcn_cvt_pk_fp8_f32(a, b, 0, false);
#else
  return (unsigned int)f2fp8_sw(a) | ((unsigned int)f2fp8_sw(b) << 8);
#endif
}

__device__ __forceinline__ void gload16(const void* g, void* l){
  __builtin_amdgcn_global_load_lds((const __attribute__((address_space(1))) unsigned int*)g,
                                   (__attribute__((address_space(3))) unsigned int*)l,
                                   16, 0, 0);
}

// ---------------- K1: normalize over C, write fb[b][t][n][c] bf16 ----------------
__global__ void k_norm(const float* __restrict__ feats, unsigned short* __restrict__ fbuf){
  int n = blockIdx.x * 256 + threadIdx.x;
  int b = blockIdx.y >> 3, t = blockIdx.y & 7;
  const float* src = feats + (((size_t)b * NC) * NT + t) * NN + n;   // feats[b][c][t][n]
  float ss = 0.f;
  #pragma unroll 8
  for(int c = 0; c < NC; c++){ float v = src[(size_t)c * NT * NN]; ss += v * v; }
  float sc = 1.f / (sqrtf(ss) + 1e-12f);
  unsigned short* dst = fbuf + (((size_t)b * NT + t) * NN + n) * NC;
  #pragma unroll 8
  for(int c = 0; c < NC; c++){ float v = src[(size_t)c * NT * NN]; dst[c] = f2bf(v * sc); }
}

// ---------------- K2/K3: E_t[m][k] = exp(<f_{t+1}[m], f_t[k]>/T) ----------------
// Double-buffered BK=32 staging, gload_lds, 0-conflict swizzle.
// MODE 0: fp32 sums c_t,r_t; ALSO store G'=E^T/16 fp8 (sigma cols) if Gall
// MODE 1: store G' only (fallback)
// MODE 2: write P0' = 65536*E0/(r0 r1), M0' = 1024*E0/c0  (fp8, sigma cols)
template<int MODE>
__global__ void gemm_small(const unsigned short* __restrict__ fbuf,
                           unsigned char* __restrict__ G,
                           float* __restrict__ rb, float* __restrict__ cb,
                           unsigned char* __restrict__ P0, unsigned char* __restrict__ M0,
                           int tsel)
{
  __shared__ __align__(16) unsigned short lA[2][128*32];
  __shared__ __align__(16) unsigned short lB[2][128*32];
  int b, t, brow, bcol;
  if(MODE == 0){
    int lin = blockIdx.x, x8 = lin & 7, q = lin >> 3;
    int blk = q & 63, g = (q >> 6) * 8 + x8;       // g in 0..111
    b = g / 7; t = g % 7;
    brow = (blk >> 3) << 7; bcol = (blk & 7) << 7;
  } else if(MODE == 2){
    int lin = blockIdx.x, x8 = lin & 7, q = lin >> 3;
    int blk = q & 63;
    b = (q >> 6) * 8 + x8; t = 0;                  // b in 0..15
    brow = (blk >> 3) << 7; bcol = (blk & 7) << 7;
  } else {
    b = blockIdx.z; t = tsel;
    brow = blockIdx.x * 128; bcol = blockIdx.y * 128;
  }
  int tA = (MODE==2) ? 0 : t+1;
  int tB = (MODE==2) ? 1 : t;
  const unsigned short* Ab = fbuf + ((size_t)(b*NT+tA)*NN + brow) * NC;
  const unsigned short* Bb = fbuf + ((size_t)(b*NT+tB)*NN + bcol) * NC;
  int tid = threadIdx.x, lane = tid & 63, w = tid >> 6, wr = w >> 1, wc = w & 1;
  int l15 = lane & 15, g4 = lane >> 4;
  int rchunk = (g4 ^ ((l15 >> 1) & 3)) << 3;       // read chunk ushort offset

  f32x4 acc[4][4];
  #pragma unroll
  for(int m=0;m<4;m++)
    #pragma unroll
    for(int n=0;n<4;n++) acc[m][n] = (f32x4){0.f,0.f,0.f,0.f};

  auto stageK = [&](int kk, unsigned short* la, unsigned short* lb){
    #pragma unroll
    for(int j = 0; j < 2; j++){
      int ch = tid + j*256;
      int row = ch >> 2, c = ch & 3;
      int sc = (c ^ ((row >> 1) & 3)) << 3;
      gload16(Ab + (size_t)row*NC + kk*32 + sc, la + ch*8);
      gload16(Bb + (size_t)row*NC + kk*32 + sc, lb + ch*8);
    }
  };
  auto computeK = [&](const unsigned short* la, const unsigned short* lb){
    bf16x8 fa[4], fg[4];
    #pragma unroll
    for(int x=0;x<4;x++){
      fa[x] = *(const bf16x8*)(la + (wr*64 + x*16 + l15)*32 + rchunk);
      fg[x] = *(const bf16x8*)(lb + (wc*64 + x*16 + l15)*32 + rchunk);
    }
    #pragma unroll
    for(int m=0;m<4;m++)
      #pragma unroll
      for(int n=0;n<4;n++)
        acc[m][n] = __builtin_amdgcn_mfma_f32_16x16x32_bf16(fa[m], fg[n], acc[m][n], 0, 0, 0);
  };

  stageK(0, lA[0], lB[0]);
  __syncthreads();
  stageK(1, lA[1], lB[1]);
  computeK(lA[0], lB[0]);
  __syncthreads();
  stageK(2, lA[0], lB[0]);
  computeK(lA[1], lB[1]);
  __syncthreads();
  stageK(3, lA[1], lB[1]);
  computeK(lA[0], lB[0]);
  __syncthreads();
  computeK(lA[1], lB[1]);

  float e[4][4][4];
  #pragma unroll
  for(int m=0;m<4;m++)
    #pragma unroll
    for(int n=0;n<4;n++)
      #pragma unroll
      for(int j=0;j<4;j++) e[m][n][j] = __expf(acc[m][n][j] * INV_T);

  if(MODE == 0){
    float* cbt = cb + ((size_t)b*7 + t) * NN;
    float* rbt = rb + ((size_t)b*7 + t) * NN;
    #pragma unroll
    for(int m=0;m<4;m++)
      #pragma unroll
      for(int j=0;j<4;j++){
        float s = e[m][0][j]+e[m][1][j]+e[m][2][j]+e[m][3][j];
        s += __shfl_xor(s,1); s += __shfl_xor(s,2); s += __shfl_xor(s,4); s += __shfl_xor(s,8);
        if((lane & 15) == 0){
          int row = brow + wr*64 + m*16 + (lane>>4)*4 + j;
          atomicAdd(&cbt[row], s);
        }
      }
    #pragma unroll
    for(int n=0;n<4;n++){
      float s = 0.f;
      #pragma unroll
      for(int m=0;m<4;m++)
        #pragma unroll
        for(int j=0;j<4;j++) s += e[m][n][j];
      s += __shfl_xor(s,16); s += __shfl_xor(s,32);
      if((lane >> 4) == 0){
        int col = bcol + wc*64 + n*16 + lane;
        atomicAdd(&rbt[col], s);
      }
    }
    if(G && t >= 1){   // fused G' store (fp8, /16, sigma-packed u32)
      unsigned char* Gt = G + ((size_t)(t-1)*NB + b) * ((size_t)NN*NN);
      #pragma unroll
      for(int m=0;m<4;m++)
        #pragma unroll
        for(int j=0;j<4;j++){
          int row = brow + wr*64 + m*16 + (lane>>4)*4 + j;
          unsigned int p01 = pk2fp8(e[m][0][j]*0.0625f, e[m][1][j]*0.0625f);
          unsigned int p23 = pk2fp8(e[m][2][j]*0.0625f, e[m][3][j]*0.0625f);
          *(unsigned int*)(Gt + (size_t)row * NN + bcol + wc*64 + l15*4) = p01 | (p23 << 16);
        }
    }
  } else if(MODE == 1){
    unsigned char* Gt = G + ((size_t)b << 20);
    #pragma unroll
    for(int m=0;m<4;m++)
      #pragma unroll
      for(int j=0;j<4;j++){
        int row = brow + wr*64 + m*16 + (lane>>4)*4 + j;
        unsigned int p01 = pk2fp8(e[m][0][j]*0.0625f, e[m][1][j]*0.0625f);
        unsigned int p23 = pk2fp8(e[m][2][j]*0.0625f, e[m][3][j]*0.0625f);
        *(unsigned int*)(Gt + (size_t)row * NN + bcol + wc*64 + l15*4) = p01 | (p23 << 16);
      }
  } else {
    const float* r0 = rb + (size_t)b*7*NN;
    const float* r1 = r0 + NN;
    const float* c0 = cb + (size_t)b*7*NN;
    unsigned char* Pt = P0 + ((size_t)b << 20);
    unsigned char* Mt = M0 + ((size_t)b << 20);
    float r1i[4], c0i[4];
    #pragma unroll
    for(int n=0;n<4;n++){
      int col = bcol + wc*64 + n*16 + l15;
      r1i[n] = 65536.f / r1[col];
      c0i[n] = 1024.f / c0[col];
    }
    #pragma unroll
    for(int m=0;m<4;m++)
      #pragma unroll
      for(int j=0;j<4;j++){
        int row = brow + wr*64 + m*16 + (lane>>4)*4 + j;
        float r0i = 1.f / r0[row];
        unsigned int a01 = pk2fp8(e[m][0][j]*r0i*r1i[0], e[m][1][j]*r0i*r1i[1]);
        unsigned int a23 = pk2fp8(e[m][2][j]*r0i*r1i[2], e[m][3][j]*r0i*r1i[3]);
        unsigned int b01 = pk2fp8(e[m][0][j]*c0i[0], e[m][1][j]*c0i[1]);
        unsigned int b23 = pk2fp8(e[m][2][j]*c0i[2], e[m][3][j]*c0i[3]);
        *(unsigned int*)(Pt + (size_t)row * NN + bcol + wc*64 + l15*4) = a01 | (a23 << 16);
        *(unsigned int*)(Mt + (size_t)row * NN + bcol + wc*64 + l15*4) = b01 | (b23 << 16);
      }
  }
}

// ---------------- K4: fused dual chain GEMM (fp8, sigma cols) ----------------
// Retile for occupancy: BM=64, BN=128, BK=64, 256 thr (4 waves, dual 32x64/wave)
// -> acc 64 VGPR/thread, launch_bounds(256,4) -> 4 blocks/CU; LDS 32KB dbuf.
// Scales: P' = 65536 P, M' = 1024 M, G' = E^T/16.
// Batch-per-XCD grid: xcd = lin&7 owns b = xcd + 8*(q>>7); P+M+G (3MB) L2-resident.
template<int LAST>
__global__ void __launch_bounds__(256, 4)
k_chain(const unsigned char* __restrict__ P, const unsigned char* __restrict__ M,
        const unsigned char* __restrict__ G,
        unsigned char* __restrict__ Pn, unsigned char* __restrict__ Mn,
        const float* __restrict__ rb, const float* __restrict__ cb,
        float* __restrict__ diag, int i)
{
  __shared__ __align__(16) unsigned char lP0[64*64], lM0[64*64], lG0[128*64];
  __shared__ __align__(16) unsigned char lP1[64*64], lM1[64*64], lG1[128*64];
  int lin = blockIdx.x;
  int xcd = lin & 7, q = lin >> 3;                // q 0..255
  int b = xcd + 8 * (q >> 7);                     // 2 batches per XCD
  int j = q & 127;
  int rowb = j >> 3, cbk = j & 7;                 // 16 row-blocks x 8 col-blocks
  size_t mb = (size_t)b << 20;                    // plane = 1 MB (fp8)
  int brow = rowb * 64, bcol = cbk * 128;
  const unsigned char* Pb = P + mb + (size_t)brow * NN;
  const unsigned char* Mb = M + mb + (size_t)brow * NN;
  const unsigned char* Gb = G + mb + (size_t)bcol * NN;
  int tid = threadIdx.x, lane = tid & 63, w = tid >> 6, wr = w >> 1, wc = w & 1;
  int l15 = lane & 15, g4 = lane >> 4, sm = l15 & 6;

  int srow = tid >> 2;                                 // 0..63
  int gOff = (((tid & 3) ^ ((srow >> 1) & 3)) << 4);   // swizzled source byte offset
  int so0 = ((g4 ^ sm) << 3);                          // read slot byte offset (kh0); kh1 = so0^32

  f32x4 aP[2][4], aM[2][4];
  #pragma unroll
  for(int m=0;m<2;m++)
    #pragma unroll
    for(int n=0;n<4;n++){ aP[m][n] = (f32x4){0.f,0.f,0.f,0.f}; aM[m][n] = (f32x4){0.f,0.f,0.f,0.f}; }

  auto stage = [&](int kk, unsigned char* lp, unsigned char* lm, unsigned char* lg){
    const unsigned char* ps = Pb + kk*64 + gOff;
    const unsigned char* ms = Mb + kk*64 + gOff;
    const unsigned char* gs = Gb + kk*64 + gOff;
    gload16(ps + (size_t)srow*NN,      lp + tid*16);
    gload16(ms + (size_t)srow*NN,      lm + tid*16);
    gload16(gs + (size_t)srow*NN,      lg + tid*16);
    gload16(gs + (size_t)(srow+64)*NN, lg + 4096 + tid*16);
  };

  auto compute = [&](const unsigned char* lp, const unsigned char* lm, const unsigned char* lg){
    #pragma unroll
    for(int kh = 0; kh < 2; kh++){
      int so = so0 ^ (kh << 5);
      long fP[2], fM[2], fG[4];
      #pragma unroll
      for(int x=0;x<2;x++){
        fP[x] = *(const long*)(lp + (wr*32 + x*16 + l15)*64 + so);
        fM[x] = *(const long*)(lm + (wr*32 + x*16 + l15)*64 + so);
      }
      #pragma unroll
      for(int x=0;x<4;x++)
        fG[x] = *(const long*)(lg + (wc*64 + x*16 + l15)*64 + so);
      #pragma unroll
      for(int m=0;m<2;m++)
        #pragma unroll
        for(int n=0;n<4;n++){
          aP[m][n] = __builtin_amdgcn_mfma_f32_16x16x32_fp8_fp8(fP[m], fG[n], aP[m][n], 0, 0, 0);
          aM[m][n] = __builtin_amdgcn_mfma_f32_16x16x32_fp8_fp8(fM[m], fG[n], aM[m][n], 0, 0, 0);
        }
    }
  };

  stage(0, lP0, lM0, lG0);
  __syncthreads();
  #pragma unroll 1
  for(int kk = 0; kk < 16; kk += 2){
    if(kk + 1 < 16) stage(kk+1, lP1, lM1, lG1);
    compute(lP0, lM0, lG0);
    __syncthreads();
    if(kk + 2 < 16) stage(kk+2, lP0, lM0, lG0);
    compute(lP1, lM1, lG1);
    __syncthreads();
  }

  const float* ccur = cb + ((size_t)b*7 + i) * NN;
  const float* rnxt = rb + ((size_t)b*7 + i + 1) * NN;  // not dereferenced when LAST
  float cid[4], ciw[4], ri[4];
  #pragma unroll
  for(int n=0;n<4;n++){
    int col = bcol + wc*64 + n*16 + l15;
    float c1 = 1.f / ccur[col];
    cid[n] = c1;
    ciw[n] = 16.f * c1;
    ri[n]  = LAST ? 0.f : 16.f / rnxt[col];
  }
  float* dg = diag + ((size_t)b*6 + (i-1)) * NN;
  #pragma unroll
  for(int m=0;m<2;m++)
    #pragma unroll
    for(int j4=0;j4<4;j4++){
      int rowi = brow + wr*32 + m*16 + g4*4 + j4;
      float s = 0.f;
      #pragma unroll
      for(int n=0;n<4;n++)
        s += aP[m][n][j4] * aM[m][n][j4] * cid[n];
      if(!LAST){
        unsigned int a01 = pk2fp8(aP[m][0][j4]*ri[0], aP[m][1][j4]*ri[1]);
        unsigned int a23 = pk2fp8(aP[m][2][j4]*ri[2], aP[m][3][j4]*ri[3]);
        unsigned int b01 = pk2fp8(aM[m][0][j4]*ciw[0], aM[m][1][j4]*ciw[1]);
        unsigned int b23 = pk2fp8(aM[m][2][j4]*ciw[2], aM[m][3][j4]*ciw[3]);
        *(unsigned int*)(Pn + mb + (size_t)rowi * NN + bcol + wc*64 + l15*4) = a01 | (a23 << 16);
        *(unsigned int*)(Mn + mb + (size_t)rowi * NN + bcol + wc*64 + l15*4) = b01 | (b23 << 16);
      }
      s += __shfl_xor(s,1); s += __shfl_xor(s,2); s += __shfl_xor(s,4); s += __shfl_xor(s,8);
      if((lane&15)==0) atomicAdd(&dg[rowi], s * (1.f/262144.f));
    }
}

// ---------------- K5: loss = -mean log(diag + eps) ----------------
__global__ void k_loss(const float* __restrict__ diag, float* __restrict__ out){
  __shared__ float red[16];
  float s = 0.f;
  for(int idx = threadIdx.x; idx < NB*6*NN; idx += 1024) s += __logf(diag[idx] + 1e-20f);
  s += __shfl_xor(s,1); s += __shfl_xor(s,2); s += __shfl_xor(s,4);
  s += __shfl_xor(s,8); s += __shfl_xor(s,16); s += __shfl_xor(s,32);
  if((threadIdx.x & 63) == 0) red[threadIdx.x >> 6] = s;
  __syncthreads();
  if(threadIdx.x == 0){
    float t = 0.f;
    for(int k = 0; k < 16; k++) t += red[k];
    out[0] = -t / (6.0f * NB * NN);
  }
}

__global__ void k_fail(float* out){ out[0] = 1.0e9f; }

extern "C" void kernel_launch(void* const* d_in, const int* in_sizes, int n_in,
                              void* d_out, int out_size, void* d_ws, size_t ws_size,
                              hipStream_t stream) {
  const float* feats = (const float*)d_in[0];
  float* out = (float*)d_out;
  char* ws = (char*)d_ws;
  size_t off = 0;
  auto alloc = [&](size_t bytes) -> char* {
    char* p = ws + off; off += (bytes + 255) & ~(size_t)255; return p;
  };
  const size_t plane = (size_t)NB * NN * NN;                            // 16.8 MB (fp8)
  unsigned short* fb = (unsigned short*)alloc((size_t)NB*NT*NN*NC*2);   // 33.5 MB
  unsigned char* Pa   = (unsigned char*)alloc(plane);
  unsigned char* Pbuf = (unsigned char*)alloc(plane);
  unsigned char* Ma   = (unsigned char*)alloc(plane);
  unsigned char* Mbuf = (unsigned char*)alloc(plane);
  float* rb = (float*)alloc((size_t)NB*7*NN*4);
  float* cb = (float*)alloc((size_t)NB*7*NN*4);
  float* dg = (float*)alloc((size_t)NB*6*NN*4);
  if(off + plane > ws_size){ k_fail<<<1,1,0,stream>>>(out); return; }
  bool big = (off + 6*plane) <= ws_size;
  unsigned char* G = (unsigned char*)alloc(big ? 6*plane : plane);

  // zero the accumulated buffers (r, c, diag are contiguous, 256B-aligned sizes)
  hipMemsetAsync(rb, 0, (size_t)NB*7*NN*4 + (size_t)NB*7*NN*4 + (size_t)NB*6*NN*4, stream);

  k_norm<<<dim3(4, NB*NT), 256, 0, stream>>>(feats, fb);
  gemm_small<0><<<dim3(7168), 256, 0, stream>>>(fb, big ? G : nullptr, rb, cb, nullptr, nullptr, 0);
  gemm_small<2><<<dim3(1024), 256, 0, stream>>>(fb, nullptr, rb, cb, Pa, Ma, 0);

  unsigned char *Pold = Pa, *Mold = Ma, *Pnew = Pbuf, *Mnew = Mbuf;
  for(int i = 1; i <= 6; i++){
    unsigned char* Gi;
    if(big){
      Gi = G + (size_t)(i-1) * NB * NN * NN;
    } else {
      gemm_small<1><<<dim3(8,8,NB), 256, 0, stream>>>(fb, G, rb, cb, nullptr, nullptr, i);
      Gi = G;
    }
    if(i < 6)
      k_chain<0><<<dim3(2048), 256, 0, stream>>>(Pold, Mold, Gi, Pnew, Mnew, rb, cb, dg, i);
    else
      k_chain<1><<<dim3(2048), 256, 0, stream>>>(Pold, Mold, Gi, Pnew, Mnew, rb, cb, dg, i);
    unsigned char* tp = Pold; Pold = Pnew; Pnew = tp;
    unsigned char* tm = Mold; Mold = Mnew; Mnew = tm;
  }
  k_loss<<<1, 1024, 0, stream>>>(dg, out);
}

// Round 16
// 525.057 us; speedup vs baseline: 1.2360x; 1.2360x over previous
//
#include <hip/hip_runtime.h>

typedef __attribute__((ext_vector_type(4))) float f32x4;
typedef __attribute__((ext_vector_type(8))) short bf16x8;
typedef __attribute__((ext_vector_type(8))) unsigned short ushort8;
typedef __attribute__((ext_vector_type(4))) int i32x4;

#define NB 16
#define NC 128
#define NT 8
#define NN 1024
#define INV_T (1.0f/0.07f)

// k-permutation sigma: within each 64-col block of every k-indexed fp8 buffer
// (G, P, M), natural col c = n*16+l is stored at byte position l*4+n. Both GEMM
// operands use sigma => contraction unchanged. Storage additionally carries the
// 16B-chunk swizzle c_addr = c_data ^ ((row>>1)&3); k_chain reads data-chunk g4
// as one b128 and uses half0/half1 as the kh0/kh1 MFMA operands (another shared
// k-permutation => still invariant).

__device__ __forceinline__ unsigned short f2bf(float x){
  union { float f; unsigned int u; } v; v.f = x;
  unsigned int r = v.u + 0x7fffu + ((v.u >> 16) & 1u);
  return (unsigned short)(r >> 16);
}

__device__ __forceinline__ unsigned char f2fp8_sw(float x){
  if(!(x >= 9.765625e-4f)) return 0;
  if(x >= 448.f) return 0x7E;
  union { float f; unsigned int u; } v; v.f = x;
  int e = (int)((v.u >> 23) & 255) - 127;
  if(e >= -6){
    unsigned int m = v.u & 0x7FFFFFu;
    unsigned int r = m + 0x7FFFFu + ((m >> 20) & 1u);
    if(r & 0x800000u){ e++; r = 0; }
    unsigned int b = ((unsigned)(e + 7) << 3) | ((r >> 20) & 7u);
    if(b >= 0x7Fu) b = 0x7Eu;
    return (unsigned char)b;
  } else {
    float t = x * 512.f;
    int q = (int)(t + 0.5f);
    return (unsigned char)q;
  }
}

__device__ __forceinline__ unsigned int pk2fp8(float a, float b){
#if __has_builtin(__builtin_amdgcn_cvt_pk_fp8_f32)
  return (unsigned int)__builtin_amdgcn_cvt_pk_fp8_f32(a, b, 0, false);
#else
  return (unsigned int)f2fp8_sw(a) | ((unsigned int)f2fp8_sw(b) << 8);
#endif
}

__device__ __forceinline__ void gload16(const void* g, void* l){
  __builtin_amdgcn_global_load_lds((const __attribute__((address_space(1))) unsigned int*)g,
                                   (__attribute__((address_space(3))) unsigned int*)l,
                                   16, 0, 0);
}

// ---------------- K1: normalize over C, write fb[b][t][n][c] bf16 ----------------
__global__ void k_norm(const float* __restrict__ feats, unsigned short* __restrict__ fbuf){
  int n = blockIdx.x * 256 + threadIdx.x;
  int b = blockIdx.y >> 3, t = blockIdx.y & 7;
  const float* src = feats + (((size_t)b * NC) * NT + t) * NN + n;   // feats[b][c][t][n]
  float ss = 0.f;
  #pragma unroll 8
  for(int c = 0; c < NC; c++){ float v = src[(size_t)c * NT * NN]; ss += v * v; }
  float sc = 1.f / (sqrtf(ss) + 1e-12f);
  unsigned short* dst = fbuf + (((size_t)b * NT + t) * NN + n) * NC;
  #pragma unroll 8
  for(int c = 0; c < NC; c++){ float v = src[(size_t)c * NT * NN]; dst[c] = f2bf(v * sc); }
}

// ---------------- K2/K3: E_t[m][k] = exp(<f_{t+1}[m], f_t[k]>/T) ----------------
// Double-buffered BK=32 staging, gload_lds, 0-conflict swizzle.
// MODE 0: fp32 sums c_t,r_t; ALSO store G'=E^T/16 fp8 (sigma cols) if Gall
// MODE 1: store G' only (fallback)
// MODE 2: write P0' = 65536*E0/(r0 r1), M0' = 1024*E0/c0  (fp8, sigma cols)
template<int MODE>
__global__ void gemm_small(const unsigned short* __restrict__ fbuf,
                           unsigned char* __restrict__ G,
                           float* __restrict__ rb, float* __restrict__ cb,
                           unsigned char* __restrict__ P0, unsigned char* __restrict__ M0,
                           int tsel)
{
  __shared__ __align__(16) unsigned short lA[2][128*32];
  __shared__ __align__(16) unsigned short lB[2][128*32];
  int b, t, brow, bcol;
  if(MODE == 0){
    int lin = blockIdx.x, x8 = lin & 7, q = lin >> 3;
    int blk = q & 63, g = (q >> 6) * 8 + x8;       // g in 0..111
    b = g / 7; t = g % 7;
    brow = (blk >> 3) << 7; bcol = (blk & 7) << 7;
  } else if(MODE == 2){
    int lin = blockIdx.x, x8 = lin & 7, q = lin >> 3;
    int blk = q & 63;
    b = (q >> 6) * 8 + x8; t = 0;                  // b in 0..15
    brow = (blk >> 3) << 7; bcol = (blk & 7) << 7;
  } else {
    b = blockIdx.z; t = tsel;
    brow = blockIdx.x * 128; bcol = blockIdx.y * 128;
  }
  int tA = (MODE==2) ? 0 : t+1;
  int tB = (MODE==2) ? 1 : t;
  const unsigned short* Ab = fbuf + ((size_t)(b*NT+tA)*NN + brow) * NC;
  const unsigned short* Bb = fbuf + ((size_t)(b*NT+tB)*NN + bcol) * NC;
  int tid = threadIdx.x, lane = tid & 63, w = tid >> 6, wr = w >> 1, wc = w & 1;
  int l15 = lane & 15, g4 = lane >> 4;
  int rchunk = (g4 ^ ((l15 >> 1) & 3)) << 3;       // read chunk ushort offset

  f32x4 acc[4][4];
  #pragma unroll
  for(int m=0;m<4;m++)
    #pragma unroll
    for(int n=0;n<4;n++) acc[m][n] = (f32x4){0.f,0.f,0.f,0.f};

  auto stageK = [&](int kk, unsigned short* la, unsigned short* lb){
    #pragma unroll
    for(int j = 0; j < 2; j++){
      int ch = tid + j*256;
      int row = ch >> 2, c = ch & 3;
      int sc = (c ^ ((row >> 1) & 3)) << 3;
      gload16(Ab + (size_t)row*NC + kk*32 + sc, la + ch*8);
      gload16(Bb + (size_t)row*NC + kk*32 + sc, lb + ch*8);
    }
  };
  auto computeK = [&](const unsigned short* la, const unsigned short* lb){
    bf16x8 fa[4], fg[4];
    #pragma unroll
    for(int x=0;x<4;x++){
      fa[x] = *(const bf16x8*)(la + (wr*64 + x*16 + l15)*32 + rchunk);
      fg[x] = *(const bf16x8*)(lb + (wc*64 + x*16 + l15)*32 + rchunk);
    }
    #pragma unroll
    for(int m=0;m<4;m++)
      #pragma unroll
      for(int n=0;n<4;n++)
        acc[m][n] = __builtin_amdgcn_mfma_f32_16x16x32_bf16(fa[m], fg[n], acc[m][n], 0, 0, 0);
  };

  stageK(0, lA[0], lB[0]);
  __syncthreads();
  stageK(1, lA[1], lB[1]);
  computeK(lA[0], lB[0]);
  __syncthreads();
  stageK(2, lA[0], lB[0]);
  computeK(lA[1], lB[1]);
  __syncthreads();
  stageK(3, lA[1], lB[1]);
  computeK(lA[0], lB[0]);
  __syncthreads();
  computeK(lA[1], lB[1]);

  float e[4][4][4];
  #pragma unroll
  for(int m=0;m<4;m++)
    #pragma unroll
    for(int n=0;n<4;n++)
      #pragma unroll
      for(int j=0;j<4;j++) e[m][n][j] = __expf(acc[m][n][j] * INV_T);

  if(MODE == 0){
    float* cbt = cb + ((size_t)b*7 + t) * NN;
    float* rbt = rb + ((size_t)b*7 + t) * NN;
    #pragma unroll
    for(int m=0;m<4;m++)
      #pragma unroll
      for(int j=0;j<4;j++){
        float s = e[m][0][j]+e[m][1][j]+e[m][2][j]+e[m][3][j];
        s += __shfl_xor(s,1); s += __shfl_xor(s,2); s += __shfl_xor(s,4); s += __shfl_xor(s,8);
        if((lane & 15) == 0){
          int row = brow + wr*64 + m*16 + (lane>>4)*4 + j;
          atomicAdd(&cbt[row], s);
        }
      }
    #pragma unroll
    for(int n=0;n<4;n++){
      float s = 0.f;
      #pragma unroll
      for(int m=0;m<4;m++)
        #pragma unroll
        for(int j=0;j<4;j++) s += e[m][n][j];
      s += __shfl_xor(s,16); s += __shfl_xor(s,32);
      if((lane >> 4) == 0){
        int col = bcol + wc*64 + n*16 + lane;
        atomicAdd(&rbt[col], s);
      }
    }
    if(G && t >= 1){   // fused G' store (fp8, /16, sigma-packed u32)
      unsigned char* Gt = G + ((size_t)(t-1)*NB + b) * ((size_t)NN*NN);
      #pragma unroll
      for(int m=0;m<4;m++)
        #pragma unroll
        for(int j=0;j<4;j++){
          int row = brow + wr*64 + m*16 + (lane>>4)*4 + j;
          unsigned int p01 = pk2fp8(e[m][0][j]*0.0625f, e[m][1][j]*0.0625f);
          unsigned int p23 = pk2fp8(e[m][2][j]*0.0625f, e[m][3][j]*0.0625f);
          *(unsigned int*)(Gt + (size_t)row * NN + bcol + wc*64 + l15*4) = p01 | (p23 << 16);
        }
    }
  } else if(MODE == 1){
    unsigned char* Gt = G + ((size_t)b << 20);
    #pragma unroll
    for(int m=0;m<4;m++)
      #pragma unroll
      for(int j=0;j<4;j++){
        int row = brow + wr*64 + m*16 + (lane>>4)*4 + j;
        unsigned int p01 = pk2fp8(e[m][0][j]*0.0625f, e[m][1][j]*0.0625f);
        unsigned int p23 = pk2fp8(e[m][2][j]*0.0625f, e[m][3][j]*0.0625f);
        *(unsigned int*)(Gt + (size_t)row * NN + bcol + wc*64 + l15*4) = p01 | (p23 << 16);
      }
  } else {
    const float* r0 = rb + (size_t)b*7*NN;
    const float* r1 = r0 + NN;
    const float* c0 = cb + (size_t)b*7*NN;
    unsigned char* Pt = P0 + ((size_t)b << 20);
    unsigned char* Mt = M0 + ((size_t)b << 20);
    float r1i[4], c0i[4];
    #pragma unroll
    for(int n=0;n<4;n++){
      int col = bcol + wc*64 + n*16 + l15;
      r1i[n] = 65536.f / r1[col];
      c0i[n] = 1024.f / c0[col];
    }
    #pragma unroll
    for(int m=0;m<4;m++)
      #pragma unroll
      for(int j=0;j<4;j++){
        int row = brow + wr*64 + m*16 + (lane>>4)*4 + j;
        float r0i = 1.f / r0[row];
        unsigned int a01 = pk2fp8(e[m][0][j]*r0i*r1i[0], e[m][1][j]*r0i*r1i[1]);
        unsigned int a23 = pk2fp8(e[m][2][j]*r0i*r1i[2], e[m][3][j]*r0i*r1i[3]);
        unsigned int b01 = pk2fp8(e[m][0][j]*c0i[0], e[m][1][j]*c0i[1]);
        unsigned int b23 = pk2fp8(e[m][2][j]*c0i[2], e[m][3][j]*c0i[3]);
        *(unsigned int*)(Pt + (size_t)row * NN + bcol + wc*64 + l15*4) = a01 | (a23 << 16);
        *(unsigned int*)(Mt + (size_t)row * NN + bcol + wc*64 + l15*4) = b01 | (b23 << 16);
      }
  }
}

// ---------------- K4: fused dual chain GEMM (fp8, sigma cols), tile 128x256, BK=64 ----------------
// Scales: P' = 65536 P, M' = 1024 M, G' = E^T/16.
// b128 fragment reads (data-chunk g4 at addr-chunk g4^((l15>>1)&3)) — proven
// conflict-free pattern; half0/half1 feed the kh0/kh1 MFMAs.
// Batch-per-XCD grid: xcd = lin&7 owns b = xcd + 8*(wq>>5).
template<int LAST>
__global__ void __launch_bounds__(512, 2)
k_chain(const unsigned char* __restrict__ P, const unsigned char* __restrict__ M,
        const unsigned char* __restrict__ G,
        unsigned char* __restrict__ Pn, unsigned char* __restrict__ Mn,
        const float* __restrict__ rb, const float* __restrict__ cb,
        float* __restrict__ diag, int i)
{
  __shared__ __align__(16) unsigned char lP0[128*64], lM0[128*64], lG0[256*64];
  __shared__ __align__(16) unsigned char lP1[128*64], lM1[128*64], lG1[256*64];
  int lin = blockIdx.x;
  int xcd = lin & 7, wq = lin >> 3;               // wq 0..63
  int b = xcd + 8 * (wq >> 5);                    // 2 batches per XCD
  int j = wq & 31;
  int rowb = j >> 2, cbk = j & 3;
  size_t mb = (size_t)b << 20;                    // plane = 1 MB (fp8)
  int brow = rowb * 128, bcol = cbk * 256;
  const unsigned char* Pb = P + mb + (size_t)brow * NN;
  const unsigned char* Mb = M + mb + (size_t)brow * NN;
  const unsigned char* Gb = G + mb + (size_t)bcol * NN;
  int tid = threadIdx.x, lane = tid & 63, w = tid >> 6, wr = w >> 2, wc = w & 3;
  int l15 = lane & 15, g4 = lane >> 4;

  int srow = tid >> 2;
  int gOff = (((tid & 3) ^ ((srow >> 1) & 3)) << 4);   // swizzled source byte offset
  int c16 = ((g4 ^ ((l15 >> 1) & 3)) << 4);            // b128 read chunk byte offset

  f32x4 aP[4][4], aM[4][4];
  #pragma unroll
  for(int m=0;m<4;m++)
    #pragma unroll
    for(int n=0;n<4;n++){ aP[m][n] = (f32x4){0.f,0.f,0.f,0.f}; aM[m][n] = (f32x4){0.f,0.f,0.f,0.f}; }

  auto stage = [&](int kk, unsigned char* lp, unsigned char* lm, unsigned char* lg){
    const unsigned char* ps = Pb + kk*64 + gOff;
    const unsigned char* ms = Mb + kk*64 + gOff;
    const unsigned char* gs = Gb + kk*64 + gOff;
    gload16(ps + (size_t)srow*NN,       lp + tid*16);
    gload16(ms + (size_t)srow*NN,       lm + tid*16);
    gload16(gs + (size_t)srow*NN,       lg + tid*16);
    gload16(gs + (size_t)(srow+128)*NN, lg + 8192 + tid*16);
  };

  auto compute = [&](const unsigned char* lp, const unsigned char* lm, const unsigned char* lg){
    union LD { i32x4 v; long q[2]; };
    LD fP[4], fM[4], fG[4];
    #pragma unroll
    for(int x=0;x<4;x++){
      fP[x].v = *(const i32x4*)(lp + (wr*64 + x*16 + l15)*64 + c16);
      fM[x].v = *(const i32x4*)(lm + (wr*64 + x*16 + l15)*64 + c16);
      fG[x].v = *(const i32x4*)(lg + (wc*64 + x*16 + l15)*64 + c16);
    }
    #pragma unroll
    for(int kh = 0; kh < 2; kh++){
      #pragma unroll
      for(int m=0;m<4;m++)
        #pragma unroll
        for(int n=0;n<4;n++){
          aP[m][n] = __builtin_amdgcn_mfma_f32_16x16x32_fp8_fp8(fP[m].q[kh], fG[n].q[kh], aP[m][n], 0, 0, 0);
          aM[m][n] = __builtin_amdgcn_mfma_f32_16x16x32_fp8_fp8(fM[m].q[kh], fG[n].q[kh], aM[m][n], 0, 0, 0);
        }
    }
  };

  stage(0, lP0, lM0, lG0);
  __syncthreads();
  #pragma unroll 1
  for(int kk = 0; kk < 16; kk += 2){
    if(kk + 1 < 16) stage(kk+1, lP1, lM1, lG1);
    compute(lP0, lM0, lG0);
    __syncthreads();
    if(kk + 2 < 16) stage(kk+2, lP0, lM0, lG0);
    compute(lP1, lM1, lG1);
    __syncthreads();
  }

  const float* ccur = cb + ((size_t)b*7 + i) * NN;
  const float* rnxt = rb + ((size_t)b*7 + i + 1) * NN;  // not dereferenced when LAST
  float cid[4], ciw[4], ri[4];
  #pragma unroll
  for(int n=0;n<4;n++){
    int col = bcol + wc*64 + n*16 + l15;
    float c1 = 1.f / ccur[col];
    cid[n] = c1;
    ciw[n] = 16.f * c1;
    ri[n]  = LAST ? 0.f : 16.f / rnxt[col];
  }
  float* dg = diag + ((size_t)b*6 + (i-1)) * NN;
  #pragma unroll
  for(int m=0;m<4;m++)
    #pragma unroll
    for(int j4=0;j4<4;j4++){
      int rowi = brow + wr*64 + m*16 + g4*4 + j4;
      float s = 0.f;
      #pragma unroll
      for(int n=0;n<4;n++)
        s += aP[m][n][j4] * aM[m][n][j4] * cid[n];
      if(!LAST){
        unsigned int a01 = pk2fp8(aP[m][0][j4]*ri[0], aP[m][1][j4]*ri[1]);
        unsigned int a23 = pk2fp8(aP[m][2][j4]*ri[2], aP[m][3][j4]*ri[3]);
        unsigned int b01 = pk2fp8(aM[m][0][j4]*ciw[0], aM[m][1][j4]*ciw[1]);
        unsigned int b23 = pk2fp8(aM[m][2][j4]*ciw[2], aM[m][3][j4]*ciw[3]);
        *(unsigned int*)(Pn + mb + (size_t)rowi * NN + bcol + wc*64 + l15*4) = a01 | (a23 << 16);
        *(unsigned int*)(Mn + mb + (size_t)rowi * NN + bcol + wc*64 + l15*4) = b01 | (b23 << 16);
      }
      s += __shfl_xor(s,1); s += __shfl_xor(s,2); s += __shfl_xor(s,4); s += __shfl_xor(s,8);
      if((lane&15)==0) atomicAdd(&dg[rowi], s * (1.f/262144.f));
    }
}

// ---------------- K5: loss = -mean log(diag + eps) ----------------
__global__ void k_loss(const float* __restrict__ diag, float* __restrict__ out){
  __shared__ float red[16];
  float s = 0.f;
  for(int idx = threadIdx.x; idx < NB*6*NN; idx += 1024) s += __logf(diag[idx] + 1e-20f);
  s += __shfl_xor(s,1); s += __shfl_xor(s,2); s += __shfl_xor(s,4);
  s += __shfl_xor(s,8); s += __shfl_xor(s,16); s += __shfl_xor(s,32);
  if((threadIdx.x & 63) == 0) red[threadIdx.x >> 6] = s;
  __syncthreads();
  if(threadIdx.x == 0){
    float t = 0.f;
    for(int k = 0; k < 16; k++) t += red[k];
    out[0] = -t / (6.0f * NB * NN);
  }
}

__global__ void k_fail(float* out){ out[0] = 1.0e9f; }

extern "C" void kernel_launch(void* const* d_in, const int* in_sizes, int n_in,
                              void* d_out, int out_size, void* d_ws, size_t ws_size,
                              hipStream_t stream) {
  const float* feats = (const float*)d_in[0];
  float* out = (float*)d_out;
  char* ws = (char*)d_ws;
  size_t off = 0;
  auto alloc = [&](size_t bytes) -> char* {
    char* p = ws + off; off += (bytes + 255) & ~(size_t)255; return p;
  };
  const size_t plane = (size_t)NB * NN * NN;                            // 16.8 MB (fp8)
  unsigned short* fb = (unsigned short*)alloc((size_t)NB*NT*NN*NC*2);   // 33.5 MB
  unsigned char* Pa   = (unsigned char*)alloc(plane);
  unsigned char* Pbuf = (unsigned char*)alloc(plane);
  unsigned char* Ma   = (unsigned char*)alloc(plane);
  unsigned char* Mbuf = (unsigned char*)alloc(plane);
  float* rb = (float*)alloc((size_t)NB*7*NN*4);
  float* cb = (float*)alloc((size_t)NB*7*NN*4);
  float* dg = (float*)alloc((size_t)NB*6*NN*4);
  if(off + plane > ws_size){ k_fail<<<1,1,0,stream>>>(out); return; }
  bool big = (off + 6*plane) <= ws_size;
  unsigned char* G = (unsigned char*)alloc(big ? 6*plane : plane);

  // zero the accumulated buffers (r, c, diag are contiguous, 256B-aligned sizes)
  hipMemsetAsync(rb, 0, (size_t)NB*7*NN*4 + (size_t)NB*7*NN*4 + (size_t)NB*6*NN*4, stream);

  k_norm<<<dim3(4, NB*NT), 256, 0, stream>>>(feats, fb);
  gemm_small<0><<<dim3(7168), 256, 0, stream>>>(fb, big ? G : nullptr, rb, cb, nullptr, nullptr, 0);
  gemm_small<2><<<dim3(1024), 256, 0, stream>>>(fb, nullptr, rb, cb, Pa, Ma, 0);

  unsigned char *Pold = Pa, *Mold = Ma, *Pnew = Pbuf, *Mnew = Mbuf;
  for(int i = 1; i <= 6; i++){
    unsigned char* Gi;
    if(big){
      Gi = G + (size_t)(i-1) * NB * NN * NN;
    } else {
      gemm_small<1><<<dim3(8,8,NB), 256, 0, stream>>>(fb, G, rb, cb, nullptr, nullptr, i);
      Gi = G;
    }
    if(i < 6)
      k_chain<0><<<dim3(512), 512, 0, stream>>>(Pold, Mold, Gi, Pnew, Mnew, rb, cb, dg, i);
    else
      k_chain<1><<<dim3(512), 512, 0, stream>>>(Pold, Mold, Gi, Pnew, Mnew, rb, cb, dg, i);
    unsigned char* tp = Pold; Pold = Pnew; Pnew = tp;
    unsigned char* tm = Mold; Mold = Mnew; Mnew = tm;
  }
  k_loss<<<1, 1024, 0, stream>>>(dg, out);
}

// Round 17
// 492.985 us; speedup vs baseline: 1.3164x; 1.0651x over previous
//
#include <hip/hip_runtime.h>

typedef __attribute__((ext_vector_type(4))) float f32x4;
typedef __attribute__((ext_vector_type(8))) short bf16x8;
typedef __attribute__((ext_vector_type(8))) unsigned short ushort8;
typedef __attribute__((ext_vector_type(4))) int i32x4;

#define NB 16
#define NC 128
#define NT 8
#define NN 1024
#define INV_T (1.0f/0.07f)

// k-permutation sigma: within each 64-col block of every k-indexed fp8 buffer
// (G, P, M), natural col c = n*16+l is stored at byte position l*4+n. Both GEMM
// operands use sigma => contraction unchanged. Storage carries the 16B-chunk
// swizzle c_addr = c_data ^ ((row>>1)&3); k_chain reads data-chunk g4 as one
// b128; half0/half1 feed the kh0/kh1 MFMAs (shared k-permutation => invariant).

__device__ __forceinline__ unsigned short f2bf(float x){
  union { float f; unsigned int u; } v; v.f = x;
  unsigned int r = v.u + 0x7fffu + ((v.u >> 16) & 1u);
  return (unsigned short)(r >> 16);
}

__device__ __forceinline__ unsigned char f2fp8_sw(float x){
  if(!(x >= 9.765625e-4f)) return 0;
  if(x >= 448.f) return 0x7E;
  union { float f; unsigned int u; } v; v.f = x;
  int e = (int)((v.u >> 23) & 255) - 127;
  if(e >= -6){
    unsigned int m = v.u & 0x7FFFFFu;
    unsigned int r = m + 0x7FFFFu + ((m >> 20) & 1u);
    if(r & 0x800000u){ e++; r = 0; }
    unsigned int b = ((unsigned)(e + 7) << 3) | ((r >> 20) & 7u);
    if(b >= 0x7Fu) b = 0x7Eu;
    return (unsigned char)b;
  } else {
    float t = x * 512.f;
    int q = (int)(t + 0.5f);
    return (unsigned char)q;
  }
}

__device__ __forceinline__ unsigned int pk2fp8(float a, float b){
#if __has_builtin(__builtin_amdgcn_cvt_pk_fp8_f32)
  return (unsigned int)__builtin_amdgcn_cvt_pk_fp8_f32(a, b, 0, false);
#else
  return (unsigned int)f2fp8_sw(a) | ((unsigned int)f2fp8_sw(b) << 8);
#endif
}

__device__ __forceinline__ void gload16(const void* g, void* l){
  __builtin_amdgcn_global_load_lds((const __attribute__((address_space(1))) unsigned int*)g,
                                   (__attribute__((address_space(3))) unsigned int*)l,
                                   16, 0, 0);
}

// ---------------- K1: normalize over C, write fb[b][t][n][c] bf16 ----------------
__global__ void k_norm(const float* __restrict__ feats, unsigned short* __restrict__ fbuf){
  int n = blockIdx.x * 256 + threadIdx.x;
  int b = blockIdx.y >> 3, t = blockIdx.y & 7;
  const float* src = feats + (((size_t)b * NC) * NT + t) * NN + n;   // feats[b][c][t][n]
  float ss = 0.f;
  #pragma unroll 8
  for(int c = 0; c < NC; c++){ float v = src[(size_t)c * NT * NN]; ss += v * v; }
  float sc = 1.f / (sqrtf(ss) + 1e-12f);
  unsigned short* dst = fbuf + (((size_t)b * NT + t) * NN + n) * NC;
  #pragma unroll 8
  for(int c = 0; c < NC; c++){ float v = src[(size_t)c * NT * NN]; dst[c] = f2bf(v * sc); }
}

// ---------------- K2/K3: E_t[m][k] = exp(<f_{t+1}[m], f_t[k]>/T) ----------------
// Double-buffered BK=32 staging, gload_lds, 0-conflict swizzle.
// MODE 0: fp32 sums c_t,r_t; ALSO store G'=E^T/16 fp8 (sigma cols) if Gall
// MODE 1: store G' only (fallback)
// MODE 2: write P0' = 65536*E0/(r0 r1), M0' = 1024*E0/c0  (fp8, sigma cols)
template<int MODE>
__global__ void gemm_small(const unsigned short* __restrict__ fbuf,
                           unsigned char* __restrict__ G,
                           float* __restrict__ rb, float* __restrict__ cb,
                           unsigned char* __restrict__ P0, unsigned char* __restrict__ M0,
                           int tsel)
{
  __shared__ __align__(16) unsigned short lA[2][128*32];
  __shared__ __align__(16) unsigned short lB[2][128*32];
  int b, t, brow, bcol;
  if(MODE == 0){
    int lin = blockIdx.x, x8 = lin & 7, q = lin >> 3;
    int blk = q & 63, g = (q >> 6) * 8 + x8;       // g in 0..111
    b = g / 7; t = g % 7;
    brow = (blk >> 3) << 7; bcol = (blk & 7) << 7;
  } else if(MODE == 2){
    int lin = blockIdx.x, x8 = lin & 7, q = lin >> 3;
    int blk = q & 63;
    b = (q >> 6) * 8 + x8; t = 0;                  // b in 0..15
    brow = (blk >> 3) << 7; bcol = (blk & 7) << 7;
  } else {
    b = blockIdx.z; t = tsel;
    brow = blockIdx.x * 128; bcol = blockIdx.y * 128;
  }
  int tA = (MODE==2) ? 0 : t+1;
  int tB = (MODE==2) ? 1 : t;
  const unsigned short* Ab = fbuf + ((size_t)(b*NT+tA)*NN + brow) * NC;
  const unsigned short* Bb = fbuf + ((size_t)(b*NT+tB)*NN + bcol) * NC;
  int tid = threadIdx.x, lane = tid & 63, w = tid >> 6, wr = w >> 1, wc = w & 1;
  int l15 = lane & 15, g4 = lane >> 4;
  int rchunk = (g4 ^ ((l15 >> 1) & 3)) << 3;       // read chunk ushort offset

  f32x4 acc[4][4];
  #pragma unroll
  for(int m=0;m<4;m++)
    #pragma unroll
    for(int n=0;n<4;n++) acc[m][n] = (f32x4){0.f,0.f,0.f,0.f};

  auto stageK = [&](int kk, unsigned short* la, unsigned short* lb){
    #pragma unroll
    for(int j = 0; j < 2; j++){
      int ch = tid + j*256;
      int row = ch >> 2, c = ch & 3;
      int sc = (c ^ ((row >> 1) & 3)) << 3;
      gload16(Ab + (size_t)row*NC + kk*32 + sc, la + ch*8);
      gload16(Bb + (size_t)row*NC + kk*32 + sc, lb + ch*8);
    }
  };
  auto computeK = [&](const unsigned short* la, const unsigned short* lb){
    bf16x8 fa[4], fg[4];
    #pragma unroll
    for(int x=0;x<4;x++){
      fa[x] = *(const bf16x8*)(la + (wr*64 + x*16 + l15)*32 + rchunk);
      fg[x] = *(const bf16x8*)(lb + (wc*64 + x*16 + l15)*32 + rchunk);
    }
    #pragma unroll
    for(int m=0;m<4;m++)
      #pragma unroll
      for(int n=0;n<4;n++)
        acc[m][n] = __builtin_amdgcn_mfma_f32_16x16x32_bf16(fa[m], fg[n], acc[m][n], 0, 0, 0);
  };

  stageK(0, lA[0], lB[0]);
  __syncthreads();
  stageK(1, lA[1], lB[1]);
  computeK(lA[0], lB[0]);
  __syncthreads();
  stageK(2, lA[0], lB[0]);
  computeK(lA[1], lB[1]);
  __syncthreads();
  stageK(3, lA[1], lB[1]);
  computeK(lA[0], lB[0]);
  __syncthreads();
  computeK(lA[1], lB[1]);

  float e[4][4][4];
  #pragma unroll
  for(int m=0;m<4;m++)
    #pragma unroll
    for(int n=0;n<4;n++)
      #pragma unroll
      for(int j=0;j<4;j++) e[m][n][j] = __expf(acc[m][n][j] * INV_T);

  if(MODE == 0){
    float* cbt = cb + ((size_t)b*7 + t) * NN;
    float* rbt = rb + ((size_t)b*7 + t) * NN;
    #pragma unroll
    for(int m=0;m<4;m++)
      #pragma unroll
      for(int j=0;j<4;j++){
        float s = e[m][0][j]+e[m][1][j]+e[m][2][j]+e[m][3][j];
        s += __shfl_xor(s,1); s += __shfl_xor(s,2); s += __shfl_xor(s,4); s += __shfl_xor(s,8);
        if((lane & 15) == 0){
          int row = brow + wr*64 + m*16 + (lane>>4)*4 + j;
          atomicAdd(&cbt[row], s);
        }
      }
    #pragma unroll
    for(int n=0;n<4;n++){
      float s = 0.f;
      #pragma unroll
      for(int m=0;m<4;m++)
        #pragma unroll
        for(int j=0;j<4;j++) s += e[m][n][j];
      s += __shfl_xor(s,16); s += __shfl_xor(s,32);
      if((lane >> 4) == 0){
        int col = bcol + wc*64 + n*16 + lane;
        atomicAdd(&rbt[col], s);
      }
    }
    if(G && t >= 1){   // fused G' store (fp8, /16, sigma-packed u32)
      unsigned char* Gt = G + ((size_t)(t-1)*NB + b) * ((size_t)NN*NN);
      #pragma unroll
      for(int m=0;m<4;m++)
        #pragma unroll
        for(int j=0;j<4;j++){
          int row = brow + wr*64 + m*16 + (lane>>4)*4 + j;
          unsigned int p01 = pk2fp8(e[m][0][j]*0.0625f, e[m][1][j]*0.0625f);
          unsigned int p23 = pk2fp8(e[m][2][j]*0.0625f, e[m][3][j]*0.0625f);
          *(unsigned int*)(Gt + (size_t)row * NN + bcol + wc*64 + l15*4) = p01 | (p23 << 16);
        }
    }
  } else if(MODE == 1){
    unsigned char* Gt = G + ((size_t)b << 20);
    #pragma unroll
    for(int m=0;m<4;m++)
      #pragma unroll
      for(int j=0;j<4;j++){
        int row = brow + wr*64 + m*16 + (lane>>4)*4 + j;
        unsigned int p01 = pk2fp8(e[m][0][j]*0.0625f, e[m][1][j]*0.0625f);
        unsigned int p23 = pk2fp8(e[m][2][j]*0.0625f, e[m][3][j]*0.0625f);
        *(unsigned int*)(Gt + (size_t)row * NN + bcol + wc*64 + l15*4) = p01 | (p23 << 16);
      }
  } else {
    const float* r0 = rb + (size_t)b*7*NN;
    const float* r1 = r0 + NN;
    const float* c0 = cb + (size_t)b*7*NN;
    unsigned char* Pt = P0 + ((size_t)b << 20);
    unsigned char* Mt = M0 + ((size_t)b << 20);
    float r1i[4], c0i[4];
    #pragma unroll
    for(int n=0;n<4;n++){
      int col = bcol + wc*64 + n*16 + l15;
      r1i[n] = 65536.f / r1[col];
      c0i[n] = 1024.f / c0[col];
    }
    #pragma unroll
    for(int m=0;m<4;m++)
      #pragma unroll
      for(int j=0;j<4;j++){
        int row = brow + wr*64 + m*16 + (lane>>4)*4 + j;
        float r0i = 1.f / r0[row];
        unsigned int a01 = pk2fp8(e[m][0][j]*r0i*r1i[0], e[m][1][j]*r0i*r1i[1]);
        unsigned int a23 = pk2fp8(e[m][2][j]*r0i*r1i[2], e[m][3][j]*r0i*r1i[3]);
        unsigned int b01 = pk2fp8(e[m][0][j]*c0i[0], e[m][1][j]*c0i[1]);
        unsigned int b23 = pk2fp8(e[m][2][j]*c0i[2], e[m][3][j]*c0i[3]);
        *(unsigned int*)(Pt + (size_t)row * NN + bcol + wc*64 + l15*4) = a01 | (a23 << 16);
        *(unsigned int*)(Mt + (size_t)row * NN + bcol + wc*64 + l15*4) = b01 | (b23 << 16);
      }
  }
}

// ---------------- K4: fused dual chain GEMM (fp8, sigma cols) ----------------
// Tile 128x128, BK=64, 256 thr (4 waves, dual 64x64/wave) — per-thread acc
// unchanged (128 regs) but smaller block => 2 blocks/CU co-resident (m114
// overlap hides the per-step barrier drain). LDS 48KB dbuf. b128 reads.
// Grid 1024: batch x's 64 blocks land exactly on XCD x's 64 block-slots.
// Scales: P' = 65536 P, M' = 1024 M, G' = E^T/16.
template<int LAST>
__global__ void __launch_bounds__(256, 2)
k_chain(const unsigned char* __restrict__ P, const unsigned char* __restrict__ M,
        const unsigned char* __restrict__ G,
        unsigned char* __restrict__ Pn, unsigned char* __restrict__ Mn,
        const float* __restrict__ rb, const float* __restrict__ cb,
        float* __restrict__ diag, int i)
{
  __shared__ __align__(16) unsigned char lP0[128*64], lM0[128*64], lG0[128*64];
  __shared__ __align__(16) unsigned char lP1[128*64], lM1[128*64], lG1[128*64];
  int lin = blockIdx.x;
  int xcd = lin & 7, q = lin >> 3;                // q 0..127
  int b = xcd + 8 * (q >> 6);                     // 2 batches per XCD
  int j = q & 63;
  int rowb = j >> 3, cbk = j & 7;                 // 8 x 8 blocks of 128x128
  size_t mb = (size_t)b << 20;                    // plane = 1 MB (fp8)
  int brow = rowb * 128, bcol = cbk * 128;
  const unsigned char* Pb = P + mb + (size_t)brow * NN;
  const unsigned char* Mb = M + mb + (size_t)brow * NN;
  const unsigned char* Gb = G + mb + (size_t)bcol * NN;
  int tid = threadIdx.x, lane = tid & 63, w = tid >> 6, wr = w >> 1, wc = w & 1;
  int l15 = lane & 15, g4 = lane >> 4;

  int c16 = ((g4 ^ ((l15 >> 1) & 3)) << 4);       // b128 read chunk byte offset

  f32x4 aP[4][4], aM[4][4];
  #pragma unroll
  for(int m=0;m<4;m++)
    #pragma unroll
    for(int n=0;n<4;n++){ aP[m][n] = (f32x4){0.f,0.f,0.f,0.f}; aM[m][n] = (f32x4){0.f,0.f,0.f,0.f}; }

  auto stage = [&](int kk, unsigned char* lp, unsigned char* lm, unsigned char* lg){
    #pragma unroll
    for(int jj = 0; jj < 2; jj++){
      int ch = tid + jj*256;
      int row = ch >> 2, c = ch & 3;
      int so = ((c ^ ((row >> 1) & 3)) << 4);
      size_t ga = (size_t)row * NN + kk*64 + so;
      gload16(Pb + ga, lp + ch*16);
      gload16(Mb + ga, lm + ch*16);
      gload16(Gb + ga, lg + ch*16);
    }
  };

  auto compute = [&](const unsigned char* lp, const unsigned char* lm, const unsigned char* lg){
    union LD { i32x4 v; long qd[2]; };
    LD fP[4], fM[4], fG[4];
    #pragma unroll
    for(int x=0;x<4;x++){
      fP[x].v = *(const i32x4*)(lp + (wr*64 + x*16 + l15)*64 + c16);
      fM[x].v = *(const i32x4*)(lm + (wr*64 + x*16 + l15)*64 + c16);
      fG[x].v = *(const i32x4*)(lg + (wc*64 + x*16 + l15)*64 + c16);
    }
    #pragma unroll
    for(int kh = 0; kh < 2; kh++){
      #pragma unroll
      for(int m=0;m<4;m++)
        #pragma unroll
        for(int n=0;n<4;n++){
          aP[m][n] = __builtin_amdgcn_mfma_f32_16x16x32_fp8_fp8(fP[m].qd[kh], fG[n].qd[kh], aP[m][n], 0, 0, 0);
          aM[m][n] = __builtin_amdgcn_mfma_f32_16x16x32_fp8_fp8(fM[m].qd[kh], fG[n].qd[kh], aM[m][n], 0, 0, 0);
        }
    }
  };

  stage(0, lP0, lM0, lG0);
  __syncthreads();
  #pragma unroll 1
  for(int kk = 0; kk < 16; kk += 2){
    if(kk + 1 < 16) stage(kk+1, lP1, lM1, lG1);
    compute(lP0, lM0, lG0);
    __syncthreads();
    if(kk + 2 < 16) stage(kk+2, lP0, lM0, lG0);
    compute(lP1, lM1, lG1);
    __syncthreads();
  }

  const float* ccur = cb + ((size_t)b*7 + i) * NN;
  const float* rnxt = rb + ((size_t)b*7 + i + 1) * NN;  // not dereferenced when LAST
  float cid[4], ciw[4], ri[4];
  #pragma unroll
  for(int n=0;n<4;n++){
    int col = bcol + wc*64 + n*16 + l15;
    float c1 = 1.f / ccur[col];
    cid[n] = c1;
    ciw[n] = 16.f * c1;
    ri[n]  = LAST ? 0.f : 16.f / rnxt[col];
  }
  float* dg = diag + ((size_t)b*6 + (i-1)) * NN;
  #pragma unroll
  for(int m=0;m<4;m++)
    #pragma unroll
    for(int j4=0;j4<4;j4++){
      int rowi = brow + wr*64 + m*16 + g4*4 + j4;
      float s = 0.f;
      #pragma unroll
      for(int n=0;n<4;n++)
        s += aP[m][n][j4] * aM[m][n][j4] * cid[n];
      if(!LAST){
        unsigned int a01 = pk2fp8(aP[m][0][j4]*ri[0], aP[m][1][j4]*ri[1]);
        unsigned int a23 = pk2fp8(aP[m][2][j4]*ri[2], aP[m][3][j4]*ri[3]);
        unsigned int b01 = pk2fp8(aM[m][0][j4]*ciw[0], aM[m][1][j4]*ciw[1]);
        unsigned int b23 = pk2fp8(aM[m][2][j4]*ciw[2], aM[m][3][j4]*ciw[3]);
        *(unsigned int*)(Pn + mb + (size_t)rowi * NN + bcol + wc*64 + l15*4) = a01 | (a23 << 16);
        *(unsigned int*)(Mn + mb + (size_t)rowi * NN + bcol + wc*64 + l15*4) = b01 | (b23 << 16);
      }
      s += __shfl_xor(s,1); s += __shfl_xor(s,2); s += __shfl_xor(s,4); s += __shfl_xor(s,8);
      if((lane&15)==0) atomicAdd(&dg[rowi], s * (1.f/262144.f));
    }
}

// ---------------- K5: loss = -mean log(diag + eps) ----------------
__global__ void k_loss(const float* __restrict__ diag, float* __restrict__ out){
  __shared__ float red[16];
  float s = 0.f;
  for(int idx = threadIdx.x; idx < NB*6*NN; idx += 1024) s += __logf(diag[idx] + 1e-20f);
  s += __shfl_xor(s,1); s += __shfl_xor(s,2); s += __shfl_xor(s,4);
  s += __shfl_xor(s,8); s += __shfl_xor(s,16); s += __shfl_xor(s,32);
  if((threadIdx.x & 63) == 0) red[threadIdx.x >> 6] = s;
  __syncthreads();
  if(threadIdx.x == 0){
    float t = 0.f;
    for(int k = 0; k < 16; k++) t += red[k];
    out[0] = -t / (6.0f * NB * NN);
  }
}

__global__ void k_fail(float* out){ out[0] = 1.0e9f; }

extern "C" void kernel_launch(void* const* d_in, const int* in_sizes, int n_in,
                              void* d_out, int out_size, void* d_ws, size_t ws_size,
                              hipStream_t stream) {
  const float* feats = (const float*)d_in[0];
  float* out = (float*)d_out;
  char* ws = (char*)d_ws;
  size_t off = 0;
  auto alloc = [&](size_t bytes) -> char* {
    char* p = ws + off; off += (bytes + 255) & ~(size_t)255; return p;
  };
  const size_t plane = (size_t)NB * NN * NN;                            // 16.8 MB (fp8)
  unsigned short* fb = (unsigned short*)alloc((size_t)NB*NT*NN*NC*2);   // 33.5 MB
  unsigned char* Pa   = (unsigned char*)alloc(plane);
  unsigned char* Pbuf = (unsigned char*)alloc(plane);
  unsigned char* Ma   = (unsigned char*)alloc(plane);
  unsigned char* Mbuf = (unsigned char*)alloc(plane);
  float* rbv = (float*)alloc((size_t)NB*7*NN*4);
  float* cbv = (float*)alloc((size_t)NB*7*NN*4);
  float* dg = (float*)alloc((size_t)NB*6*NN*4);
  if(off + plane > ws_size){ k_fail<<<1,1,0,stream>>>(out); return; }
  bool big = (off + 6*plane) <= ws_size;
  unsigned char* G = (unsigned char*)alloc(big ? 6*plane : plane);

  // zero the accumulated buffers (r, c, diag are contiguous, 256B-aligned sizes)
  hipMemsetAsync(rbv, 0, (size_t)NB*7*NN*4 + (size_t)NB*7*NN*4 + (size_t)NB*6*NN*4, stream);

  k_norm<<<dim3(4, NB*NT), 256, 0, stream>>>(feats, fb);
  gemm_small<0><<<dim3(7168), 256, 0, stream>>>(fb, big ? G : nullptr, rbv, cbv, nullptr, nullptr, 0);
  gemm_small<2><<<dim3(1024), 256, 0, stream>>>(fb, nullptr, rbv, cbv, Pa, Ma, 0);

  unsigned char *Pold = Pa, *Mold = Ma, *Pnew = Pbuf, *Mnew = Mbuf;
  for(int i = 1; i <= 6; i++){
    unsigned char* Gi;
    if(big){
      Gi = G + (size_t)(i-1) * NB * NN * NN;
    } else {
      gemm_small<1><<<dim3(8,8,NB), 256, 0, stream>>>(fb, G, rbv, cbv, nullptr, nullptr, i);
      Gi = G;
    }
    if(i < 6)
      k_chain<0><<<dim3(1024), 256, 0, stream>>>(Pold, Mold, Gi, Pnew, Mnew, rbv, cbv, dg, i);
    else
      k_chain<1><<<dim3(1024), 256, 0, stream>>>(Pold, Mold, Gi, Pnew, Mnew, rbv, cbv, dg, i);
    unsigned char* tp = Pold; Pold = Pnew; Pnew = tp;
    unsigned char* tm = Mold; Mold = Mnew; Mnew = tm;
  }
  k_loss<<<1, 1024, 0, stream>>>(dg, out);
}